// Round 4
// baseline (280.678 us; speedup 1.0000x reference)
//
#include <hip/hip_runtime.h>

// B=4096, L=64, D=128, counts in [0,64].
#define DD   128
#define LLEN 64
#define TMAX 65            // table rows: count values 0..64
#define ROWS_PER_BLK 4     // one wave (64 lanes) per batch row
#define TAB4 (TMAX * (DD / 4))   // 2080 float4 = 33280 B

// Kernel 1: tab[a][e] = b2[e] + sum_d relu(a*W1[d]+b1[d]) * W2[d][e]
// (b2 folded in: out = tab[A0] + tab[A1] yields ... + 2*b2 as required)
__global__ void build_table_kernel(const float* __restrict__ W1,
                                   const float* __restrict__ b1,
                                   const float* __restrict__ W2,
                                   const float* __restrict__ b2,
                                   float* __restrict__ tab) {
    const int a = blockIdx.x;    // 0..64
    const int e = threadIdx.x;   // 0..127
    const float fa = (float)a;
    float acc = b2[e];
#pragma unroll 8
    for (int d = 0; d < DD; ++d) {
        float h = fmaxf(fmaf(fa, W1[d], b1[d]), 0.f);
        acc = fmaf(h, W2[d * DD + e], acc);
    }
    tab[a * DD + e] = acc;
}

// Kernel 2: 4 batch rows per block, one wave per row. Table in LDS; counts
// and per-row index packs live entirely in registers (shuffle-distributed),
// so the store loop has a single-level LDS access (table row) per output.
__global__ __launch_bounds__(256) void nif_main_kernel(
    const int* __restrict__ src_id, const int* __restrict__ dst_id,
    const int* __restrict__ src_nb, const int* __restrict__ dst_nb,
    const float* __restrict__ tab, float* __restrict__ out, int B) {
    __shared__ float4 TAB[TAB4];                      // 33280 B (only LDS use)

    const int tid  = threadIdx.x;
    const int w    = tid >> 6;        // wave id 0..3
    const int lane = tid & 63;        // lane == L-row for the count phase
    const int b    = blockIdx.x * ROWS_PER_BLK + w;   // this wave's batch row

    // Per-lane neighbor values (lane <-> L-row)
    const int vs = src_nb[(size_t)b * LLEN + lane];
    const int vd = dst_nb[(size_t)b * LLEN + lane];

    // Stage table into LDS (coalesced; 2080 float4 / 256 threads)
    const float4* __restrict__ tabg = (const float4*)tab;
    for (int i = tid; i < TAB4; i += 256) TAB[i] = tabg[i];

    // Count phase — all in registers via cross-lane ops.
    const int sid = src_id[b];
    const int did = dst_id[b];
    const int cd_sid = __popcll(__ballot(vd == sid));  // count of src_id in D
    const int cs_did = __popcll(__ballot(vs == did));  // count of dst_id in S
    int c_src = 0, c_dos = 0, c_dst = 0, c_sod = 0;
#pragma unroll 8
    for (int j = 0; j < LLEN; ++j) {
        const int sj = __shfl(vs, j);
        const int dj = __shfl(vd, j);
        c_src += (sj == vs);   // count of S[i] in S
        c_dos += (dj == vs);   // count of S[i] in D
        c_dst += (dj == vd);   // count of D[i] in D
        c_sod += (sj == vd);   // count of D[i] in S
    }
    const bool s_in_d = (cd_sid > 0);
    const bool same   = (sid == did);
    const bool c2     = (cs_did > 0) || (same && s_in_d);
    const int  v2     = (same && s_in_d) ? cd_sid : cs_did;
    const int A0 = c_src;                                   // src_app[...,0]
    const int A1 = (vs == did && c2) ? v2 : c_dos;          // src_app[...,1]
    const int C0 = (vd == sid && s_in_d) ? cd_sid : c_sod;  // dst_app[...,0]
    const int C1 = c_dst;                                   // dst_app[...,1]
    // All counts <= 64: pack into one uint32 held by lane == row.
    const int pack = A0 | (A1 << 8) | (C0 << 16) | (C1 << 24);

    __syncthreads();   // TAB ready

    float4* __restrict__ out4 = (float4*)out;
    const size_t src_base = (size_t)b * (LLEN * DD / 4);           // float4 units
    const size_t dst_base = src_base + (size_t)B * (LLEN * DD / 4);
    const int e4 = lane & 31;   // float4 column 0..31
    const int lh = lane >> 5;   // which of two L-rows this half-wave handles
#pragma unroll 8
    for (int k = 0; k < 32; ++k) {
        const int l = 2 * k + lh;              // L-row 0..63
        const int p = __shfl(pack, l);         // row l's 4 packed counts
        const int idx4 = l * 32 + e4;          // wave writes 2KB contiguous
        const float4 t0 = TAB[(p & 0xFF) * 32 + e4];
        const float4 t1 = TAB[((p >> 8) & 0xFF) * 32 + e4];
        float4 v;
        v.x = t0.x + t1.x;
        v.y = t0.y + t1.y;
        v.z = t0.z + t1.z;
        v.w = t0.w + t1.w;
        out4[src_base + idx4] = v;
        const float4 u0 = TAB[((p >> 16) & 0xFF) * 32 + e4];
        const float4 u1 = TAB[((p >> 24) & 0xFF) * 32 + e4];
        float4 wv;
        wv.x = u0.x + u1.x;
        wv.y = u0.y + u1.y;
        wv.z = u0.z + u1.z;
        wv.w = u0.w + u1.w;
        out4[dst_base + idx4] = wv;
    }
}

extern "C" void kernel_launch(void* const* d_in, const int* in_sizes, int n_in,
                              void* d_out, int out_size, void* d_ws, size_t ws_size,
                              hipStream_t stream) {
    const int*   src_id = (const int*)d_in[0];
    const int*   dst_id = (const int*)d_in[1];
    const int*   src_nb = (const int*)d_in[2];
    const int*   dst_nb = (const int*)d_in[3];
    const float* W1     = (const float*)d_in[4];
    const float* b1     = (const float*)d_in[5];
    const float* W2     = (const float*)d_in[6];
    const float* b2     = (const float*)d_in[7];
    float*       out    = (float*)d_out;
    float*       tab    = (float*)d_ws;   // 65*128 fp32 = 33280 B scratch

    const int B = in_sizes[0];

    build_table_kernel<<<TMAX, DD, 0, stream>>>(W1, b1, W2, b2, tab);
    nif_main_kernel<<<B / ROWS_PER_BLK, 256, 0, stream>>>(
        src_id, dst_id, src_nb, dst_nb, tab, out, B);
}